// Round 4
// baseline (391.271 us; speedup 1.0000x reference)
//
#include <hip/hip_runtime.h>
#include <math.h>

// ---------------------------------------------------------------------------
// SpatialProximityHead on MI355X — round 3: single persistent mega-kernel.
// 256 blocks x 256 threads (1 block/CU, guaranteed co-resident: 52KB LDS),
// device-scope atomic grid barrier between phases. 11 barriers replace 16
// kernel-launch gaps. softmax fused into PV; residual+LN fused into o-proj.
// ---------------------------------------------------------------------------

#define NTOK 512
#define HDIM 256
#define DKH  64
#define NHEAD 4
#define TLEN 6
#define NBLK 256
#define NTHR 256
#define AGENT __HIP_MEMORY_SCOPE_AGENT

struct MP {
    const float *qf, *pl, *fcW, *fcb;
    const float *Wq, *bq, *Wk, *bk, *Wv, *bv, *Wo, *bo, *lng, *lnb;
    const float *m1W, *m1b, *m2W, *m2b, *cW1, *cb1, *cW2, *cb2;
    float *dist, *dwraw, *inv_cs, *x, *q, *k, *v, *ao, *S, *out;
    unsigned *bar;   // [0]=cnt, [1]=gen
};

// ---------------------------------------------------------------------------
__device__ __forceinline__ void gbar(unsigned* bar)
{
    __syncthreads();
    if (threadIdx.x == 0) {
        __threadfence();
        unsigned* cnt = bar;
        unsigned* gen = bar + 1;
        const unsigned g = __hip_atomic_load(gen, __ATOMIC_RELAXED, AGENT);
        const unsigned a = __hip_atomic_fetch_add(cnt, 1u, __ATOMIC_ACQ_REL, AGENT);
        if (a == NBLK - 1u) {
            __hip_atomic_store(cnt, 0u, __ATOMIC_RELAXED, AGENT);
            __hip_atomic_fetch_add(gen, 1u, __ATOMIC_ACQ_REL, AGENT);
        } else {
            while (__hip_atomic_load(gen, __ATOMIC_RELAXED, AGENT) == g)
                __builtin_amdgcn_s_sleep(2);
        }
        __threadfence();
    }
    __syncthreads();
}

// ---------------------------------------------------------------------------
// dist + dwraw, 4 rows per item (items 0..127).
// ---------------------------------------------------------------------------
__device__ void dist_item(const float* pl, float* dist, float* dwraw, int item)
{
    __syncthreads();
    const int t = threadIdx.x;
    const int n = item * 4 + (t >> 6);
    const int lane = t & 63;
    const float qex = pl[n * 33 + 30];
    const float qey = pl[n * 33 + 31];
    const float qez = pl[n * 33 + 32];
#pragma unroll
    for (int u = 0; u < 8; ++u) {
        const int m = lane + u * 64;
        const float dx = pl[m * 33 + 0] - qex;
        const float dy = pl[m * 33 + 1] - qey;
        const float dz = pl[m * 33 + 2] - qez;
        const float dd = sqrtf(dx * dx + dy * dy + dz * dz);
        dist[n * NTOK + m]  = dd;
        dwraw[n * NTOK + m] = 1.0f / (dd + 0.01f);
    }
}

// colsum: 32 cols per item (items 0..15). inv_cs[m] = 1/sum_n dwraw[n][m]
__device__ void colsum_item(const float* dwraw, float* inv_cs, int item, float* sm)
{
    __syncthreads();
    float* red = sm;   // [8][32]
    const int t = threadIdx.x;
    const int m = item * 32 + (t & 31);
    const int ng = t >> 5;
    float s = 0.f;
    for (int n = ng * 64; n < ng * 64 + 64; ++n) s += dwraw[n * NTOK + m];
    red[ng * 32 + (t & 31)] = s;
    __syncthreads();
    if (t < 32) {
        float a = 0.f;
#pragma unroll
        for (int g = 0; g < 8; ++g) a += red[g * 32 + t];
        inv_cs[item * 32 + t] = 1.0f / a;
    }
}

// ---------------------------------------------------------------------------
// GEMM tile: C[32x32] = A(512x256) @ W(256x256) + b. K-split-2 across
// thread-halves, tile = (rowTile<<3)|colTile, 128 tiles per problem.
// ---------------------------------------------------------------------------
__device__ void gemm_tile(const float* __restrict__ A, const float* __restrict__ W,
                          const float* __restrict__ bias, float* __restrict__ C,
                          int tile, int relu, float* sm)
{
    __syncthreads();
    float* Ast  = sm;          // [2][32][36] = 2304
    float* Wst  = sm + 2304;   // [2][32][36] = 2304
    float* exch = sm + 4608;   // [32][32]    = 1024

    const int t    = threadIdx.x;
    const int half = t >> 7;
    const int tt   = t & 127;
    const int tx   = tt & 7, ty = tt >> 3;
    const int row0 = (tile >> 3) * 32;
    const int col0 = (tile & 7) * 32;

    float* As = Ast + half * 1152;
    float* Ws = Wst + half * 1152;

    float acc[2][4] = {};

    for (int kt = 0; kt < 4; ++kt) {
        const int k0 = half * 128 + kt * 32;
#pragma unroll
        for (int j = 0; j < 2; ++j) {
            const int i  = tt * 2 + j;
            const int r  = i >> 3, c4 = i & 7;
            const float4 av = *(const float4*)&A[(row0 + r) * HDIM + k0 + c4 * 4];
            As[(c4 * 4 + 0) * 36 + r] = av.x;
            As[(c4 * 4 + 1) * 36 + r] = av.y;
            As[(c4 * 4 + 2) * 36 + r] = av.z;
            As[(c4 * 4 + 3) * 36 + r] = av.w;
            *(float4*)&Ws[r * 36 + c4 * 4] =
                *(const float4*)&W[(k0 + r) * HDIM + col0 + c4 * 4];
        }
        __syncthreads();
#pragma unroll
        for (int kk = 0; kk < 32; ++kk) {
            const float2 a = *(const float2*)&As[kk * 36 + ty * 2];
            const float4 w = *(const float4*)&Ws[kk * 36 + tx * 4];
            acc[0][0] += a.x * w.x; acc[0][1] += a.x * w.y;
            acc[0][2] += a.x * w.z; acc[0][3] += a.x * w.w;
            acc[1][0] += a.y * w.x; acc[1][1] += a.y * w.y;
            acc[1][2] += a.y * w.z; acc[1][3] += a.y * w.w;
        }
        __syncthreads();
    }

    if (half == 1) {
#pragma unroll
        for (int ii = 0; ii < 2; ++ii) {
            float4 o; o.x = acc[ii][0]; o.y = acc[ii][1];
            o.z = acc[ii][2]; o.w = acc[ii][3];
            *(float4*)&exch[(ty * 2 + ii) * 32 + tx * 4] = o;
        }
    }
    __syncthreads();
    if (half == 0) {
        float bb[4];
#pragma unroll
        for (int jj = 0; jj < 4; ++jj)
            bb[jj] = bias ? bias[col0 + tx * 4 + jj] : 0.f;
#pragma unroll
        for (int ii = 0; ii < 2; ++ii) {
            const float4 other = *(const float4*)&exch[(ty * 2 + ii) * 32 + tx * 4];
            float4 o;
            o.x = acc[ii][0] + other.x + bb[0];
            o.y = acc[ii][1] + other.y + bb[1];
            o.z = acc[ii][2] + other.z + bb[2];
            o.w = acc[ii][3] + other.w + bb[3];
            if (relu) {
                o.x = fmaxf(o.x, 0.f); o.y = fmaxf(o.y, 0.f);
                o.z = fmaxf(o.z, 0.f); o.w = fmaxf(o.w, 0.f);
            }
            *(float4*)&C[(row0 + ty * 2 + ii) * HDIM + col0 + tx * 4] = o;
        }
    }
}

// ---------------------------------------------------------------------------
// qkt tile: S[h][n0..n0+31][m0..m0+63] = q.k^T/8 + bias. 512 items:
// h = item>>7; r2 = item&127: n-tile = r2>>3 (x32), m-tile = r2&7 (x64).
// ---------------------------------------------------------------------------
__device__ void qkt_tile(const float* __restrict__ q, const float* __restrict__ k,
                         const float* __restrict__ dist, const float* __restrict__ dwraw,
                         const float* __restrict__ inv_cs, float* __restrict__ S,
                         int item, float* sm)
{
    __syncthreads();
    float* Qs = sm;          // [64][36] (d-major)
    float* Ks = sm + 2304;   // [64][68] (d-major)

    const int h  = item >> 7;
    const int r2 = item & 127;
    const int n0 = (r2 >> 3) * 32;
    const int m0 = (r2 & 7) * 64;
    const int t  = threadIdx.x;

#pragma unroll
    for (int j = 0; j < 2; ++j) {
        const int i = t + j * 256;
        const int r = i >> 4, c4 = i & 15;
        const float4 v4 = *(const float4*)&q[(n0 + r) * HDIM + h * DKH + c4 * 4];
        Qs[(c4 * 4 + 0) * 36 + r] = v4.x;
        Qs[(c4 * 4 + 1) * 36 + r] = v4.y;
        Qs[(c4 * 4 + 2) * 36 + r] = v4.z;
        Qs[(c4 * 4 + 3) * 36 + r] = v4.w;
    }
#pragma unroll
    for (int j = 0; j < 4; ++j) {
        const int i = t + j * 256;
        const int r = i >> 4, c4 = i & 15;
        const float4 v4 = *(const float4*)&k[(m0 + r) * HDIM + h * DKH + c4 * 4];
        Ks[(c4 * 4 + 0) * 68 + r] = v4.x;
        Ks[(c4 * 4 + 1) * 68 + r] = v4.y;
        Ks[(c4 * 4 + 2) * 68 + r] = v4.z;
        Ks[(c4 * 4 + 3) * 68 + r] = v4.w;
    }
    __syncthreads();

    const int tx = t & 15, ty = t >> 4;
    float acc[2][4] = {};
#pragma unroll 8
    for (int kk = 0; kk < 64; ++kk) {
        const float2 a2 = *(const float2*)&Qs[kk * 36 + ty * 2];
        const float4 b4 = *(const float4*)&Ks[kk * 68 + tx * 4];
        acc[0][0] += a2.x * b4.x; acc[0][1] += a2.x * b4.y;
        acc[0][2] += a2.x * b4.z; acc[0][3] += a2.x * b4.w;
        acc[1][0] += a2.y * b4.x; acc[1][1] += a2.y * b4.y;
        acc[1][2] += a2.y * b4.z; acc[1][3] += a2.y * b4.w;
    }

    const int m = m0 + tx * 4;
#pragma unroll
    for (int ii = 0; ii < 2; ++ii) {
        const int n = n0 + ty * 2 + ii;
        float4 bias = {0.f, 0.f, 0.f, 0.f};
        if (h == 0) {
            const float4 dw = *(const float4*)&dwraw[n * NTOK + m];
            const float4 ic = *(const float4*)&inv_cs[m];
            bias.x = dw.x * ic.x; bias.y = dw.y * ic.y;
            bias.z = dw.z * ic.z; bias.w = dw.w * ic.w;
        } else if (h == 1) {
            const float4 dd = *(const float4*)&dist[n * NTOK + m];
            bias.x = -dd.x; bias.y = -dd.y; bias.z = -dd.z; bias.w = -dd.w;
        }
        float4 o;
        o.x = acc[ii][0] * 0.125f + bias.x;
        o.y = acc[ii][1] * 0.125f + bias.y;
        o.z = acc[ii][2] * 0.125f + bias.z;
        o.w = acc[ii][3] * 0.125f + bias.w;
        *(float4*)&S[(h * NTOK + n) * NTOK + m] = o;
    }
}

// ---------------------------------------------------------------------------
// pvsm: fused softmax + P@V for 8 q-rows of one head. 256 items:
// h = item>>6, n0 = (item&63)*8. Writes ao[n][h*64+..]. Full K=512 (k-split-2
// inside block). Softmax: pass1 rowmax, pass2 exp-in-place + rowsum.
// ---------------------------------------------------------------------------
__device__ void pvsm_item(float* __restrict__ S, const float* __restrict__ v,
                          float* __restrict__ ao, int item, float* sm)
{
    __syncthreads();
    float* Vs   = sm;            // [128][68] = 8704
    float* Ps   = sm + 8704;     // [128][9]  = 1152
    float* rm   = sm + 9856;     // [8]
    float* ri   = sm + 9864;     // [8]
    float* exch = sm + 9872;     // [128] float4 = 512 floats

    const int h  = item >> 6;
    const int n0 = (item & 63) * 8;
    const int t  = threadIdx.x;
    float* Srow0 = S + (h * NTOK + n0) * NTOK;

    const int row = t >> 5, j = t & 31;   // 8 rows x 32 thr, 16 m each
    {
        const float* sr = Srow0 + row * NTOK + j * 16;
        float mx = -1e30f;
#pragma unroll
        for (int u = 0; u < 4; ++u) {
            const float4 s4 = *(const float4*)&sr[u * 4];
            mx = fmaxf(mx, fmaxf(fmaxf(s4.x, s4.y), fmaxf(s4.z, s4.w)));
        }
#pragma unroll
        for (int o = 16; o; o >>= 1) mx = fmaxf(mx, __shfl_xor(mx, o, 32));
        if (j == 0) rm[row] = mx;
    }
    __syncthreads();
    {
        const float mx = rm[row];
        float* sr = Srow0 + row * NTOK + j * 16;
        float sum = 0.f;
#pragma unroll
        for (int u = 0; u < 4; ++u) {
            float4 s4 = *(float4*)&sr[u * 4];
            s4.x = __expf(s4.x - mx); s4.y = __expf(s4.y - mx);
            s4.z = __expf(s4.z - mx); s4.w = __expf(s4.w - mx);
            sum += s4.x + s4.y + s4.z + s4.w;
            *(float4*)&sr[u * 4] = s4;
        }
#pragma unroll
        for (int o = 16; o; o >>= 1) sum += __shfl_xor(sum, o, 32);
        if (j == 0) ri[row] = 1.0f / sum;
    }
    __syncthreads();

    const int tx = t & 15, prow = (t >> 4) & 7, kh = t >> 7;
    const int rp = t >> 7, kkl = t & 127;
    float4 acc = {0.f, 0.f, 0.f, 0.f};

    for (int ch = 0; ch < 4; ++ch) {
        const int kb = ch * 128;
#pragma unroll
        for (int u = 0; u < 8; ++u) {
            const int i = t + u * 256;
            const int r = i >> 4, c4 = i & 15;
            *(float4*)&Vs[r * 68 + c4 * 4] =
                *(const float4*)&v[(kb + r) * HDIM + h * DKH + c4 * 4];
        }
#pragma unroll
        for (int u = 0; u < 4; ++u) {
            const int r = rp * 4 + u;
            Ps[kkl * 9 + r] = Srow0[r * NTOK + kb + kkl] * ri[r];
        }
        __syncthreads();
        const float* vsb = Vs + tx * 4 + kh * 64 * 68;
        const float* psb = Ps + kh * 64 * 9 + prow;
#pragma unroll 8
        for (int kk = 0; kk < 64; ++kk) {
            const float  p  = psb[kk * 9];
            const float4 vv = *(const float4*)&vsb[kk * 68];
            acc.x += p * vv.x; acc.y += p * vv.y;
            acc.z += p * vv.z; acc.w += p * vv.w;
        }
        __syncthreads();
    }

    if (kh == 1) *(float4*)&exch[(prow * 16 + tx) * 4] = acc;
    __syncthreads();
    if (kh == 0) {
        const float4 o = *(const float4*)&exch[(prow * 16 + tx) * 4];
        float4 r;
        r.x = acc.x + o.x; r.y = acc.y + o.y;
        r.z = acc.z + o.z; r.w = acc.w + o.w;
        *(float4*)&ao[(n0 + prow) * HDIM + h * DKH + tx * 4] = r;
    }
}

// ---------------------------------------------------------------------------
// oprojln: 4 rows per item (128 items): tmp = ao@Wo + bo; x = LN(x+tmp)*g+b.
// thread = output col c. Row-complete -> LN in-block, x updated in place.
// ---------------------------------------------------------------------------
__device__ void oprojln_item(const float* __restrict__ ao, const float* __restrict__ Wo,
                             const float* __restrict__ bo, const float* __restrict__ g,
                             const float* __restrict__ bb, float* __restrict__ x,
                             int item, float* sm)
{
    __syncthreads();
    float* aL  = sm;          // [4][256]
    float* red = sm + 1024;   // [4][4]

    const int n0 = item * 4;
    const int t  = threadIdx.x;
#pragma unroll
    for (int u = 0; u < 4; ++u) {
        const int i = t + u * 256;
        aL[i] = ao[(n0 + (i >> 8)) * HDIM + (i & 255)];
    }
    __syncthreads();

    float a0 = 0.f, a1 = 0.f, a2 = 0.f, a3 = 0.f;
#pragma unroll 8
    for (int d = 0; d < HDIM; ++d) {
        const float w = Wo[d * HDIM + t];
        a0 += aL[d] * w;
        a1 += aL[256 + d] * w;
        a2 += aL[512 + d] * w;
        a3 += aL[768 + d] * w;
    }
    const float bc = bo[t];
    float y[4];
    y[0] = a0 + bc + x[(n0 + 0) * HDIM + t];
    y[1] = a1 + bc + x[(n0 + 1) * HDIM + t];
    y[2] = a2 + bc + x[(n0 + 2) * HDIM + t];
    y[3] = a3 + bc + x[(n0 + 3) * HDIM + t];

    const int wv = t >> 6;
    float s0 = y[0], s1 = y[1], s2 = y[2], s3 = y[3];
#pragma unroll
    for (int o = 32; o; o >>= 1) {
        s0 += __shfl_xor(s0, o); s1 += __shfl_xor(s1, o);
        s2 += __shfl_xor(s2, o); s3 += __shfl_xor(s3, o);
    }
    if ((t & 63) == 0) {
        red[0 * 4 + wv] = s0; red[1 * 4 + wv] = s1;
        red[2 * 4 + wv] = s2; red[3 * 4 + wv] = s3;
    }
    __syncthreads();
    float mean[4];
#pragma unroll
    for (int r = 0; r < 4; ++r)
        mean[r] = (red[r * 4] + red[r * 4 + 1] + red[r * 4 + 2] + red[r * 4 + 3]) * (1.f / 256.f);
    __syncthreads();

    float c0 = y[0] - mean[0], c1 = y[1] - mean[1];
    float c2 = y[2] - mean[2], c3 = y[3] - mean[3];
    s0 = c0 * c0; s1 = c1 * c1; s2 = c2 * c2; s3 = c3 * c3;
#pragma unroll
    for (int o = 32; o; o >>= 1) {
        s0 += __shfl_xor(s0, o); s1 += __shfl_xor(s1, o);
        s2 += __shfl_xor(s2, o); s3 += __shfl_xor(s3, o);
    }
    if ((t & 63) == 0) {
        red[0 * 4 + wv] = s0; red[1 * 4 + wv] = s1;
        red[2 * 4 + wv] = s2; red[3 * 4 + wv] = s3;
    }
    __syncthreads();
    const float gg = g[t], bv2 = bb[t];
#pragma unroll
    for (int r = 0; r < 4; ++r) {
        const float var = (red[r * 4] + red[r * 4 + 1] + red[r * 4 + 2] + red[r * 4 + 3]) * (1.f / 256.f);
        const float c = (r == 0) ? c0 : (r == 1) ? c1 : (r == 2) ? c2 : c3;
        x[(n0 + r) * HDIM + t] = c * rsqrtf(var + 1e-5f) * gg + bv2;
    }
}

// ---------------------------------------------------------------------------
// pair: 32n x 16m tile (512 items): lclc = b2 + sum_h relu(U1+U2)*W2, 6 copies.
// ---------------------------------------------------------------------------
__device__ void pair_item(const float* __restrict__ U1, const float* __restrict__ U2,
                          const float* __restrict__ W2, const float* __restrict__ b2,
                          float* __restrict__ out, int item, float* sm)
{
    __syncthreads();
    float* u1s = sm;             // [32][264] = 8448
    float* u2s = sm + 8448;      // [16][264] = 4224
    float* w2s = sm + 12672;     // 256

    const int t  = threadIdx.x;
    const int n0 = (item & 15) * 32;
    const int m0 = (item >> 4) * 16;

#pragma unroll
    for (int u = 0; u < 8; ++u) {
        const int i = t + u * 256;
        *(float4*)&u1s[(i >> 6) * 264 + (i & 63) * 4] =
            *(const float4*)&U1[(n0 + (i >> 6)) * HDIM + (i & 63) * 4];
    }
#pragma unroll
    for (int u = 0; u < 4; ++u) {
        const int i = t + u * 256;
        *(float4*)&u2s[(i >> 6) * 264 + (i & 63) * 4] =
            *(const float4*)&U2[(m0 + (i >> 6)) * HDIM + (i & 63) * 4];
    }
    if (t < 64) *(float4*)&w2s[t * 4] = *(const float4*)&W2[t * 4];
    __syncthreads();

    const int tx = t & 15, ty = t >> 4;
    const float* r0 = &u1s[(ty * 2) * 264];
    const float* r1 = r0 + 264;
    const float* c0 = &u2s[tx * 264];
    float a00 = 0.f, a10 = 0.f;
#define RT(A, B) fmaxf((A) + (B), 0.f)
    for (int h4 = 0; h4 < 64; ++h4) {
        const float4 A0 = *(const float4*)&r0[h4 * 4];
        const float4 A1 = *(const float4*)&r1[h4 * 4];
        const float4 B0 = *(const float4*)&c0[h4 * 4];
        const float4 w  = *(const float4*)&w2s[h4 * 4];
        a00 += RT(A0.x,B0.x)*w.x + RT(A0.y,B0.y)*w.y + RT(A0.z,B0.z)*w.z + RT(A0.w,B0.w)*w.w;
        a10 += RT(A1.x,B0.x)*w.x + RT(A1.y,B0.y)*w.y + RT(A1.z,B0.z)*w.z + RT(A1.w,B0.w)*w.w;
    }
#undef RT
    const float bb = b2[0];
    const float v0 = a00 + bb, v1 = a10 + bb;
    const int n = n0 + ty * 2, m = m0 + tx;
#pragma unroll
    for (int tl = 0; tl < TLEN; ++tl) {
        out[tl * NTOK * NTOK + n * NTOK + m]          = v0;
        out[tl * NTOK * NTOK + (n + 1) * NTOK + m]    = v1;
    }
}

// ---------------------------------------------------------------------------
__global__ __launch_bounds__(256, 1) void mega(MP p)
{
    __shared__ __align__(16) float sm[13312];   // 52 KB phase-union

    // P1: fc gemm (128) + dist (128)
    for (int it = blockIdx.x; it < 256; it += NBLK) {
        if (it < 128) gemm_tile(p.qf, p.fcW, p.fcb, p.x, it, 1, sm);
        else          dist_item(p.pl, p.dist, p.dwraw, it - 128);
    }
    gbar(p.bar);

    for (int L = 0; L < 2; ++L) {
        const float* Wq = p.Wq + L * HDIM * HDIM;
        const float* Wk = p.Wk + L * HDIM * HDIM;
        const float* Wv = p.Wv + L * HDIM * HDIM;
        const float* Wo = p.Wo + L * HDIM * HDIM;
        const float* bq = p.bq + L * HDIM;
        const float* bk = p.bk + L * HDIM;
        const float* bv = p.bv + L * HDIM;
        const float* bo = p.bo + L * HDIM;

        // qkv (+colsum on layer 0)
        const int extra = (L == 0) ? 16 : 0;
        for (int it = blockIdx.x; it < 384 + extra; it += NBLK) {
            if (L == 0 && it < 16) {
                colsum_item(p.dwraw, p.inv_cs, it, sm);
            } else {
                const int jj = it - extra;
                const int prob = jj >> 7, tile = jj & 127;
                const float* W = (prob == 0) ? Wq : (prob == 1) ? Wk : Wv;
                const float* b = (prob == 0) ? bq : (prob == 1) ? bk : bv;
                float* C = (prob == 0) ? p.q : (prob == 1) ? p.k : p.v;
                gemm_tile(p.x, W, b, C, tile, 0, sm);
            }
        }
        gbar(p.bar);

        // qkt
        for (int it = blockIdx.x; it < 512; it += NBLK)
            qkt_tile(p.q, p.k, p.dist, p.dwraw, p.inv_cs, p.S, it, sm);
        gbar(p.bar);

        // pv + softmax
        for (int it = blockIdx.x; it < 256; it += NBLK)
            pvsm_item(p.S, p.v, p.ao, it, sm);
        gbar(p.bar);

        // o-proj + residual + LN (in-place x)
        for (int it = blockIdx.x; it < 128; it += NBLK)
            oprojln_item(p.ao, Wo, bo, p.lng + L * HDIM, p.lnb + L * HDIM,
                         p.x, it, sm);
        gbar(p.bar);
    }

    // mlp: o1 -> q, o2 -> k
    for (int it = blockIdx.x; it < 256; it += NBLK) {
        const int prob = it >> 7, tile = it & 127;
        gemm_tile(p.x, prob ? p.m2W : p.m1W, prob ? p.m2b : p.m1b,
                  prob ? p.k : p.q, tile, 1, sm);
    }
    gbar(p.bar);

    // U1 = o1@cW1[:256]+cb1 -> v ; U2 = o2@cW1[256:] -> ao
    for (int it = blockIdx.x; it < 256; it += NBLK) {
        const int prob = it >> 7, tile = it & 127;
        gemm_tile(prob ? p.k : p.q,
                  prob ? p.cW1 + HDIM * HDIM : p.cW1,
                  prob ? nullptr : p.cb1,
                  prob ? p.ao : p.v, tile, 0, sm);
    }
    gbar(p.bar);

    // pair classifier
    for (int it = blockIdx.x; it < 512; it += NBLK)
        pair_item(p.v, p.ao, p.cW2, p.cb2, p.out, it, sm);
}

// ---------------------------------------------------------------------------
extern "C" void kernel_launch(void* const* d_in, const int* in_sizes, int n_in,
                              void* d_out, int out_size, void* d_ws, size_t ws_size,
                              hipStream_t stream)
{
    const float* hs  = (const float*)d_in[0];
    const float* alp = (const float*)d_in[1];

    MP p;
    p.qf  = hs + 5 * NTOK * HDIM;
    p.pl  = alp + 5 * NTOK * 33;
    p.fcW = (const float*)d_in[2];
    p.fcb = (const float*)d_in[3];
    p.Wq  = (const float*)d_in[4];
    p.bq  = (const float*)d_in[5];
    p.Wk  = (const float*)d_in[6];
    p.bk  = (const float*)d_in[7];
    p.Wv  = (const float*)d_in[8];
    p.bv  = (const float*)d_in[9];
    p.Wo  = (const float*)d_in[10];
    p.bo  = (const float*)d_in[11];
    p.lng = (const float*)d_in[12];
    p.lnb = (const float*)d_in[13];
    p.m1W = (const float*)d_in[14];
    p.m1b = (const float*)d_in[15];
    p.m2W = (const float*)d_in[16];
    p.m2b = (const float*)d_in[17];
    p.cW1 = (const float*)d_in[18];
    p.cb1 = (const float*)d_in[19];
    p.cW2 = (const float*)d_in[20];
    p.cb2 = (const float*)d_in[21];
    p.out = (float*)d_out;

    const int NN  = NTOK * NTOK;
    const int NH_ = NTOK * HDIM;
    float* ws = (float*)d_ws;
    p.dist   = ws;                    // NN
    p.dwraw  = ws + NN;               // NN
    p.inv_cs = ws + 2 * NN;           // 512
    p.bar    = (unsigned*)(ws + 2 * NN + 512);   // 16 slots
    p.x      = ws + 2 * NN + 528;     // NH
    p.q      = p.x + NH_;
    p.k      = p.q + NH_;
    p.v      = p.k + NH_;
    p.ao     = p.v + NH_;
    p.S      = p.ao + NH_;            // 4*NN
    // total: 6*NN + 5*NH + 528 floats ~= 8.9 MB

    hipMemsetAsync((void*)p.bar, 0, 2 * sizeof(unsigned), stream);
    mega<<<NBLK, NTHR, 0, stream>>>(p);
}

// Round 5
// 134.473 us; speedup vs baseline: 2.9097x; 2.9097x over previous
//
#include <hip/hip_runtime.h>
#include <math.h>

// ---------------------------------------------------------------------------
// SpatialProximityHead on MI355X — round 4: multi-kernel, fused + packed.
// 12 dispatches: [fc+dist] [qkv+colsum] [qkt] [smpv] [oprojln] x2 layers
//                [mlp] [U] [pair]
// ---------------------------------------------------------------------------

#define NTOK 512
#define HDIM 256
#define DKH  64
#define NHEAD 4
#define TLEN 6

struct GArg { const float* A; const float* W; const float* b; float* C; };

// ---------------------------------------------------------------------------
// dist + dwraw, 4 rows per item (items 0..127), 256 threads.
// ---------------------------------------------------------------------------
__device__ void dist_item(const float* __restrict__ pl, float* __restrict__ dist,
                          float* __restrict__ dwraw, int item)
{
    const int t = threadIdx.x;
    const int n = item * 4 + (t >> 6);
    const int lane = t & 63;
    const float qex = pl[n * 33 + 30];
    const float qey = pl[n * 33 + 31];
    const float qez = pl[n * 33 + 32];
#pragma unroll
    for (int u = 0; u < 8; ++u) {
        const int m = lane + u * 64;
        const float dx = pl[m * 33 + 0] - qex;
        const float dy = pl[m * 33 + 1] - qey;
        const float dz = pl[m * 33 + 2] - qez;
        const float dd = sqrtf(dx * dx + dy * dy + dz * dz);
        dist[n * NTOK + m]  = dd;
        dwraw[n * NTOK + m] = 1.0f / (dd + 0.01f);
    }
}

// colsum: 32 cols per item (items 0..15). inv_cs[m] = 1/sum_n dwraw[n][m]
__device__ void colsum_item(const float* __restrict__ dwraw,
                            float* __restrict__ inv_cs, int item, float* sm)
{
    float* red = sm;   // [8][32]
    const int t = threadIdx.x;
    const int m = item * 32 + (t & 31);
    const int ng = t >> 5;
    float s = 0.f;
    for (int n = ng * 64; n < ng * 64 + 64; ++n) s += dwraw[n * NTOK + m];
    red[ng * 32 + (t & 31)] = s;
    __syncthreads();
    if (t < 32) {
        float a = 0.f;
#pragma unroll
        for (int g = 0; g < 8; ++g) a += red[g * 32 + t];
        inv_cs[item * 32 + t] = 1.0f / a;
    }
}

// ---------------------------------------------------------------------------
// GEMM + optional aux work. C[32x32 tile] = A(512x256)@W(256x256)+b.
// K-split-2 across thread-halves. 128 tiles per problem; problems packed on
// blockIdx.x (128 blocks each). aux: 1 = dist items at bid>=128,
// 2 = colsum items at bid>=384.
// ---------------------------------------------------------------------------
__global__ __launch_bounds__(256) void gemm_multi(
    GArg g0, GArg g1, GArg g2, int relu, int aux,
    const float* __restrict__ pl, float* __restrict__ dist,
    float* __restrict__ dwraw, float* __restrict__ inv_cs)
{
    __shared__ __align__(16) float sm[5632];   // Ast 2304 | Wst 2304 | exch 1024
    const int bid = blockIdx.x;

    if (aux == 1 && bid >= 128) { dist_item(pl, dist, dwraw, bid - 128); return; }
    if (aux == 2 && bid >= 384) { colsum_item(dwraw, inv_cs, bid - 384, sm); return; }

    const GArg ga = (bid < 128) ? g0 : (bid < 256) ? g1 : g2;
    const int tile = bid & 127;
    const int t    = threadIdx.x;
    const int half = t >> 7;
    const int tt   = t & 127;
    const int tx   = tt & 7, ty = tt >> 3;
    const int row0 = (tile >> 3) * 32;
    const int col0 = (tile & 7) * 32;

    float* As   = sm + half * 1152;          // [32][36]
    float* Ws   = sm + 2304 + half * 1152;   // [32][36]
    float* exch = sm + 4608;                 // [32][32]

    float acc[2][4] = {};

    for (int kt = 0; kt < 4; ++kt) {
        const int k0 = half * 128 + kt * 32;
#pragma unroll
        for (int j = 0; j < 2; ++j) {
            const int i  = tt * 2 + j;
            const int r  = i >> 3, c4 = i & 7;
            const float4 av = *(const float4*)&ga.A[(row0 + r) * HDIM + k0 + c4 * 4];
            As[(c4 * 4 + 0) * 36 + r] = av.x;
            As[(c4 * 4 + 1) * 36 + r] = av.y;
            As[(c4 * 4 + 2) * 36 + r] = av.z;
            As[(c4 * 4 + 3) * 36 + r] = av.w;
            *(float4*)&Ws[r * 36 + c4 * 4] =
                *(const float4*)&ga.W[(k0 + r) * HDIM + col0 + c4 * 4];
        }
        __syncthreads();
#pragma unroll
        for (int kk = 0; kk < 32; ++kk) {
            const float2 a = *(const float2*)&As[kk * 36 + ty * 2];
            const float4 w = *(const float4*)&Ws[kk * 36 + tx * 4];
            acc[0][0] += a.x * w.x; acc[0][1] += a.x * w.y;
            acc[0][2] += a.x * w.z; acc[0][3] += a.x * w.w;
            acc[1][0] += a.y * w.x; acc[1][1] += a.y * w.y;
            acc[1][2] += a.y * w.z; acc[1][3] += a.y * w.w;
        }
        __syncthreads();
    }

    if (half == 1) {
#pragma unroll
        for (int ii = 0; ii < 2; ++ii) {
            float4 o; o.x = acc[ii][0]; o.y = acc[ii][1];
            o.z = acc[ii][2]; o.w = acc[ii][3];
            *(float4*)&exch[(ty * 2 + ii) * 32 + tx * 4] = o;
        }
    }
    __syncthreads();
    if (half == 0) {
        float bb[4];
#pragma unroll
        for (int jj = 0; jj < 4; ++jj)
            bb[jj] = ga.b ? ga.b[col0 + tx * 4 + jj] : 0.f;
#pragma unroll
        for (int ii = 0; ii < 2; ++ii) {
            const float4 other = *(const float4*)&exch[(ty * 2 + ii) * 32 + tx * 4];
            float4 o;
            o.x = acc[ii][0] + other.x + bb[0];
            o.y = acc[ii][1] + other.y + bb[1];
            o.z = acc[ii][2] + other.z + bb[2];
            o.w = acc[ii][3] + other.w + bb[3];
            if (relu) {
                o.x = fmaxf(o.x, 0.f); o.y = fmaxf(o.y, 0.f);
                o.z = fmaxf(o.z, 0.f); o.w = fmaxf(o.w, 0.f);
            }
            *(float4*)&ga.C[(row0 + ty * 2 + ii) * HDIM + col0 + tx * 4] = o;
        }
    }
}

// ---------------------------------------------------------------------------
// S[h][n][m] = (q_n . k_m)/8 + bias(h,n,m). Tile 32n x 64m, grid (8,16,4).
// ---------------------------------------------------------------------------
__global__ __launch_bounds__(256) void qkt_kernel(
    const float* __restrict__ q, const float* __restrict__ k,
    const float* __restrict__ dist, const float* __restrict__ dwraw,
    const float* __restrict__ inv_cs, float* __restrict__ S)
{
    const int h  = blockIdx.z;
    const int n0 = blockIdx.y * 32;
    const int m0 = blockIdx.x * 64;
    const int t  = threadIdx.x;

    __shared__ __align__(16) float Qs[64][36];
    __shared__ __align__(16) float Ks[64][68];

#pragma unroll
    for (int j = 0; j < 2; ++j) {
        const int i = t + j * 256;
        const int r = i >> 4, c4 = i & 15;
        const float4 v4 = *(const float4*)&q[(n0 + r) * HDIM + h * DKH + c4 * 4];
        Qs[c4 * 4 + 0][r] = v4.x; Qs[c4 * 4 + 1][r] = v4.y;
        Qs[c4 * 4 + 2][r] = v4.z; Qs[c4 * 4 + 3][r] = v4.w;
    }
#pragma unroll
    for (int j = 0; j < 4; ++j) {
        const int i = t + j * 256;
        const int r = i >> 4, c4 = i & 15;
        const float4 v4 = *(const float4*)&k[(m0 + r) * HDIM + h * DKH + c4 * 4];
        Ks[c4 * 4 + 0][r] = v4.x; Ks[c4 * 4 + 1][r] = v4.y;
        Ks[c4 * 4 + 2][r] = v4.z; Ks[c4 * 4 + 3][r] = v4.w;
    }
    __syncthreads();

    const int tx = t & 15, ty = t >> 4;
    float acc[2][4] = {};
#pragma unroll 8
    for (int kk = 0; kk < 64; ++kk) {
        const float2 a2 = *(const float2*)&Qs[kk][ty * 2];
        const float4 b4 = *(const float4*)&Ks[kk][tx * 4];
        acc[0][0] += a2.x * b4.x; acc[0][1] += a2.x * b4.y;
        acc[0][2] += a2.x * b4.z; acc[0][3] += a2.x * b4.w;
        acc[1][0] += a2.y * b4.x; acc[1][1] += a2.y * b4.y;
        acc[1][2] += a2.y * b4.z; acc[1][3] += a2.y * b4.w;
    }

    const int m = m0 + tx * 4;
#pragma unroll
    for (int ii = 0; ii < 2; ++ii) {
        const int n = n0 + ty * 2 + ii;
        float4 bias = {0.f, 0.f, 0.f, 0.f};
        if (h == 0) {
            const float4 dw = *(const float4*)&dwraw[n * NTOK + m];
            const float4 ic = *(const float4*)&inv_cs[m];
            bias.x = dw.x * ic.x; bias.y = dw.y * ic.y;
            bias.z = dw.z * ic.z; bias.w = dw.w * ic.w;
        } else if (h == 1) {
            const float4 dd = *(const float4*)&dist[n * NTOK + m];
            bias.x = -dd.x; bias.y = -dd.y; bias.z = -dd.z; bias.w = -dd.w;
        }
        float4 o;
        o.x = acc[ii][0] * 0.125f + bias.x;
        o.y = acc[ii][1] * 0.125f + bias.y;
        o.z = acc[ii][2] * 0.125f + bias.z;
        o.w = acc[ii][3] * 0.125f + bias.w;
        *(float4*)&S[(h * NTOK + n) * NTOK + m] = o;
    }
}

// ---------------------------------------------------------------------------
// smpv: fused softmax + full-K P@V for 8 q-rows of one head.
// grid (64, 4). Phase A: per row (32 threads, column-strided) max/exp/sum,
// raw exp stored k-major in LDS (stride 9, conflict-free). Phase B: PV with
// V streamed from global (L2), k-split-2 across thread halves, LDS combine;
// 1/rowsum folded into the final store.
// ---------------------------------------------------------------------------
__global__ __launch_bounds__(256) void smpv_kernel(
    const float* __restrict__ S, const float* __restrict__ v,
    float* __restrict__ ao)
{
    __shared__ float ps[NTOK * 9];        // [k][row] stride 9
    __shared__ float ri[8];
    __shared__ __align__(16) float exch[512];

    const int h  = blockIdx.y;
    const int n0 = blockIdx.x * 8;
    const int t  = threadIdx.x;

    // ---- Phase A: softmax stats, raw exp -> ps (k-major) ----
    {
        const int row = t >> 5, j = t & 31;
        const float* Srow = S + (h * NTOK + n0 + row) * NTOK;
        float vals[16];
        float mx = -1e30f;
#pragma unroll
        for (int u = 0; u < 16; ++u) {
            vals[u] = Srow[j + u * 32];            // coalesced across lanes
            mx = fmaxf(mx, vals[u]);
        }
#pragma unroll
        for (int o = 16; o; o >>= 1) mx = fmaxf(mx, __shfl_xor(mx, o, 32));
        float sum = 0.f;
#pragma unroll
        for (int u = 0; u < 16; ++u) {
            const float e = __expf(vals[u] - mx);
            vals[u] = e;
            sum += e;
        }
#pragma unroll
        for (int o = 16; o; o >>= 1) sum += __shfl_xor(sum, o, 32);
        if (j == 0) ri[row] = 1.0f / sum;
#pragma unroll
        for (int u = 0; u < 16; ++u)
            ps[(j + u * 32) * 9 + row] = vals[u];  // 9*j mod 32: conflict-free
    }
    __syncthreads();

    // ---- Phase B: PV ----
    const int tx = t & 15, prow = (t >> 4) & 7, kh = t >> 7;
    const float* vb = v + h * DKH + tx * 4;
    float4 acc = {0.f, 0.f, 0.f, 0.f};
#pragma unroll 8
    for (int kk = kh * 256; kk < kh * 256 + 256; ++kk) {
        const float  p  = ps[kk * 9 + prow];
        const float4 vv = *(const float4*)&vb[kk * HDIM];
        acc.x += p * vv.x; acc.y += p * vv.y;
        acc.z += p * vv.z; acc.w += p * vv.w;
    }
    if (kh == 1) *(float4*)&exch[(prow * 16 + tx) * 4] = acc;
    __syncthreads();
    if (kh == 0) {
        const float4 o = *(const float4*)&exch[(prow * 16 + tx) * 4];
        const float sc = ri[prow];
        float4 r;
        r.x = (acc.x + o.x) * sc; r.y = (acc.y + o.y) * sc;
        r.z = (acc.z + o.z) * sc; r.w = (acc.w + o.w) * sc;
        *(float4*)&ao[(n0 + prow) * HDIM + h * DKH + tx * 4] = r;
    }
}

// ---------------------------------------------------------------------------
// oprojln: 4 rows per block (128 blocks): y = ao@Wo + bo + x; x = LN(y)*g+b.
// Thread = output col; Wo streamed coalesced from L2; row-complete -> LN
// in-block, x updated in place.
// ---------------------------------------------------------------------------
__global__ __launch_bounds__(256) void oprojln_kernel(
    const float* __restrict__ ao, const float* __restrict__ Wo,
    const float* __restrict__ bo, const float* __restrict__ g,
    const float* __restrict__ bb, float* __restrict__ x)
{
    __shared__ float aL[1024];
    __shared__ float red[16];

    const int n0 = blockIdx.x * 4;
    const int t  = threadIdx.x;
#pragma unroll
    for (int u = 0; u < 4; ++u) {
        const int i = t + u * 256;
        aL[i] = ao[(n0 + (i >> 8)) * HDIM + (i & 255)];
    }
    __syncthreads();

    float a0 = 0.f, a1 = 0.f, a2 = 0.f, a3 = 0.f;
#pragma unroll 8
    for (int d = 0; d < HDIM; ++d) {
        const float w = Wo[d * HDIM + t];
        a0 += aL[d] * w;
        a1 += aL[256 + d] * w;
        a2 += aL[512 + d] * w;
        a3 += aL[768 + d] * w;
    }
    const float bc = bo[t];
    float y[4];
    y[0] = a0 + bc + x[(n0 + 0) * HDIM + t];
    y[1] = a1 + bc + x[(n0 + 1) * HDIM + t];
    y[2] = a2 + bc + x[(n0 + 2) * HDIM + t];
    y[3] = a3 + bc + x[(n0 + 3) * HDIM + t];

    const int wv = t >> 6;
    float s0 = y[0], s1 = y[1], s2 = y[2], s3 = y[3];
#pragma unroll
    for (int o = 32; o; o >>= 1) {
        s0 += __shfl_xor(s0, o); s1 += __shfl_xor(s1, o);
        s2 += __shfl_xor(s2, o); s3 += __shfl_xor(s3, o);
    }
    if ((t & 63) == 0) {
        red[0 * 4 + wv] = s0; red[1 * 4 + wv] = s1;
        red[2 * 4 + wv] = s2; red[3 * 4 + wv] = s3;
    }
    __syncthreads();
    float mean[4];
#pragma unroll
    for (int r = 0; r < 4; ++r)
        mean[r] = (red[r * 4] + red[r * 4 + 1] + red[r * 4 + 2] + red[r * 4 + 3]) * (1.f / 256.f);
    __syncthreads();

    float c0 = y[0] - mean[0], c1 = y[1] - mean[1];
    float c2 = y[2] - mean[2], c3 = y[3] - mean[3];
    s0 = c0 * c0; s1 = c1 * c1; s2 = c2 * c2; s3 = c3 * c3;
#pragma unroll
    for (int o = 32; o; o >>= 1) {
        s0 += __shfl_xor(s0, o); s1 += __shfl_xor(s1, o);
        s2 += __shfl_xor(s2, o); s3 += __shfl_xor(s3, o);
    }
    if ((t & 63) == 0) {
        red[0 * 4 + wv] = s0; red[1 * 4 + wv] = s1;
        red[2 * 4 + wv] = s2; red[3 * 4 + wv] = s3;
    }
    __syncthreads();
    const float gg = g[t], bv2 = bb[t];
#pragma unroll
    for (int r = 0; r < 4; ++r) {
        const float var = (red[r * 4] + red[r * 4 + 1] + red[r * 4 + 2] + red[r * 4 + 3]) * (1.f / 256.f);
        const float c = (r == 0) ? c0 : (r == 1) ? c1 : (r == 2) ? c2 : c3;
        x[(n0 + r) * HDIM + t] = c * rsqrtf(var + 1e-5f) * gg + bv2;
    }
}

// ---------------------------------------------------------------------------
// Pair classifier: 32x32 tile, 2x2 per thread, TL copies.
// ---------------------------------------------------------------------------
__global__ __launch_bounds__(256) void pair_cls(const float* __restrict__ U1,
                                                const float* __restrict__ U2,
                                                const float* __restrict__ W2,
                                                const float* __restrict__ b2,
                                                float* __restrict__ out)
{
    __shared__ __align__(16) float u1s[32][260];
    __shared__ __align__(16) float u2s[32][260];
    __shared__ __align__(16) float w2s[256];
    const int t  = threadIdx.x;
    const int n0 = blockIdx.y * 32, m0 = blockIdx.x * 32;

    for (int i = t; i < 32 * 64; i += 256) {
        const int r = i >> 6, c4 = i & 63;
        *(float4*)&u1s[r][c4 * 4] = *(const float4*)&U1[(n0 + r) * HDIM + c4 * 4];
        *(float4*)&u2s[r][c4 * 4] = *(const float4*)&U2[(m0 + r) * HDIM + c4 * 4];
    }
    if (t < 64) *(float4*)&w2s[t * 4] = *(const float4*)&W2[t * 4];
    __syncthreads();

    const int tx = t & 15, ty = t >> 4;
    float acc[2][2] = {};
    for (int h4 = 0; h4 < 64; ++h4) {
        const float4 a0 = *(const float4*)&u1s[ty * 2][h4 * 4];
        const float4 a1 = *(const float4*)&u1s[ty * 2 + 1][h4 * 4];
        const float4 b0 = *(const float4*)&u2s[tx * 2][h4 * 4];
        const float4 b1 = *(const float4*)&u2s[tx * 2 + 1][h4 * 4];
        const float4 w  = *(const float4*)&w2s[h4 * 4];
#define RT(A, B) fmaxf((A) + (B), 0.f)
        acc[0][0] += RT(a0.x,b0.x)*w.x + RT(a0.y,b0.y)*w.y + RT(a0.z,b0.z)*w.z + RT(a0.w,b0.w)*w.w;
        acc[0][1] += RT(a0.x,b1.x)*w.x + RT(a0.y,b1.y)*w.y + RT(a0.z,b1.z)*w.z + RT(a0.w,b1.w)*w.w;
        acc[1][0] += RT(a1.x,b0.x)*w.x + RT(a1.y,b0.y)*w.y + RT(a1.z,b0.z)*w.z + RT(a1.w,b0.w)*w.w;
        acc[1][1] += RT(a1.x,b1.x)*w.x + RT(a1.y,b1.y)*w.y + RT(a1.z,b1.z)*w.z + RT(a1.w,b1.w)*w.w;
#undef RT
    }
    const float bb = b2[0];
#pragma unroll
    for (int ii = 0; ii < 2; ++ii)
#pragma unroll
        for (int jj = 0; jj < 2; ++jj) {
            const float val = acc[ii][jj] + bb;
            const int n = n0 + ty * 2 + ii;
            const int m = m0 + tx * 2 + jj;
#pragma unroll
            for (int tl = 0; tl < TLEN; ++tl)
                out[tl * NTOK * NTOK + n * NTOK + m] = val;
        }
}

// ---------------------------------------------------------------------------
extern "C" void kernel_launch(void* const* d_in, const int* in_sizes, int n_in,
                              void* d_out, int out_size, void* d_ws, size_t ws_size,
                              hipStream_t stream)
{
    const float* hs   = (const float*)d_in[0];
    const float* qf   = hs + 5 * NTOK * HDIM;
    const float* alp  = (const float*)d_in[1];
    const float* pl   = alp + 5 * NTOK * 33;
    const float* fc_W = (const float*)d_in[2];
    const float* fc_b = (const float*)d_in[3];
    const float* Wq   = (const float*)d_in[4];
    const float* bq   = (const float*)d_in[5];
    const float* Wk   = (const float*)d_in[6];
    const float* bk   = (const float*)d_in[7];
    const float* Wv   = (const float*)d_in[8];
    const float* bv   = (const float*)d_in[9];
    const float* Wo   = (const float*)d_in[10];
    const float* bo   = (const float*)d_in[11];
    const float* lng  = (const float*)d_in[12];
    const float* lnb  = (const float*)d_in[13];
    const float* m1W  = (const float*)d_in[14];
    const float* m1b  = (const float*)d_in[15];
    const float* m2W  = (const float*)d_in[16];
    const float* m2b  = (const float*)d_in[17];
    const float* cW1  = (const float*)d_in[18];
    const float* cb1  = (const float*)d_in[19];
    const float* cW2  = (const float*)d_in[20];
    const float* cb2  = (const float*)d_in[21];
    float* out = (float*)d_out;

    const int NN  = NTOK * NTOK;
    const int NH_ = NTOK * HDIM;
    float* ws     = (float*)d_ws;
    float* dist   = ws;
    float* dwraw  = ws + NN;
    float* inv_cs = ws + 2 * NN;
    float* x      = ws + 2 * NN + 512;
    float* v      = x + NH_;
    float* ao     = v + NH_;
    float* q      = ao + NH_;
    float* k      = q + NH_;
    float* S      = k + NH_;   // 4 MB

    const GArg gz = {nullptr, nullptr, nullptr, nullptr};

    // L1: fc GEMM (blocks 0-127) + dist (blocks 128-255)
    gemm_multi<<<256, 256, 0, stream>>>(
        GArg{qf, fc_W, fc_b, x}, gz, gz, 1, 1, pl, dist, dwraw, inv_cs);

    for (int L = 0; L < 2; ++L) {
        const float* wq = Wq + L * HDIM * HDIM;
        const float* wk = Wk + L * HDIM * HDIM;
        const float* wv = Wv + L * HDIM * HDIM;
        const float* wo = Wo + L * HDIM * HDIM;

        // qkv GEMM x3 (+ colsum on layer 0)
        gemm_multi<<<(L == 0) ? 400 : 384, 256, 0, stream>>>(
            GArg{x, wq, bq + L * HDIM, q}, GArg{x, wk, bk + L * HDIM, k},
            GArg{x, wv, bv + L * HDIM, v}, 0, (L == 0) ? 2 : 0,
            pl, dist, dwraw, inv_cs);

        qkt_kernel<<<dim3(8, 16, NHEAD), 256, 0, stream>>>(
            q, k, dist, dwraw, inv_cs, S);
        smpv_kernel<<<dim3(64, NHEAD), 256, 0, stream>>>(S, v, ao);
        oprojln_kernel<<<128, 256, 0, stream>>>(
            ao, wo, bo + L * HDIM, lng + L * HDIM, lnb + L * HDIM, x);
    }

    // mlp: o1 -> q, o2 -> k
    gemm_multi<<<256, 256, 0, stream>>>(
        GArg{x, m1W, m1b, q}, GArg{x, m2W, m2b, k}, gz, 1, 0,
        pl, dist, dwraw, inv_cs);
    // U1 = o1@cW1[:256]+cb1 -> v ; U2 = o2@cW1[256:] -> ao
    gemm_multi<<<256, 256, 0, stream>>>(
        GArg{q, cW1, cb1, v}, GArg{k, cW1 + HDIM * HDIM, nullptr, ao}, gz, 0, 0,
        pl, dist, dwraw, inv_cs);

    pair_cls<<<dim3(16, 16), 256, 0, stream>>>(v, ao, cW2, cb2, out);
}